// Round 7
// baseline (106.805 us; speedup 1.0000x reference)
//
#include <hip/hip_runtime.h>
#include <math.h>
#include <type_traits>

#define D_MODEL 1024
#define N_HEADS 16
#define D_KK    64
#define B_SZ    2
#define SEQ     2048
#define M_TOTAL (B_SZ * SEQ)   // 4096

// 0.125 * log2(e): folds attention scale AND exp->exp2 conversion into Q
#define QSCALE 0.18033688011112042f

typedef __attribute__((ext_vector_type(8))) short short8;
typedef __attribute__((ext_vector_type(4))) float f32x4;

static __device__ __forceinline__ ushort f2bf(float f) {
    union { float f; unsigned u; } c; c.f = f;
    unsigned u = c.u;
    unsigned r = (u + 0x7fffu + ((u >> 16) & 1u)) >> 16;   // RNE
    return (ushort)r;
}

// pack two f32 -> two bf16 in one u32 (round-half-up + v_perm_b32)
static __device__ __forceinline__ unsigned packbf(float a, float b) {
    unsigned ua = __float_as_uint(a) + 0x8000u;
    unsigned ub = __float_as_uint(b) + 0x8000u;
    return __builtin_amdgcn_perm(ub, ua, 0x07060302u);
}

static __device__ __forceinline__ void gload16(const void* g, void* l) {
    __builtin_amdgcn_global_load_lds(
        (const __attribute__((address_space(1))) void*)g,
        (__attribute__((address_space(3))) void*)l, 16, 0, 0);
}

// ---------------------------------------------------------------------------
// fp32 -> bf16 conversion: x and the four weight matrices.
// ---------------------------------------------------------------------------
__global__ __launch_bounds__(256)
void cvt_kernel(const float* __restrict__ x,  const float* __restrict__ wq,
                const float* __restrict__ wk, const float* __restrict__ wv,
                const float* __restrict__ wo,
                ushort* __restrict__ xb,  ushort* __restrict__ wqb,
                ushort* __restrict__ wkb, ushort* __restrict__ wvb,
                ushort* __restrict__ wob)
{
    const float* s; ushort* d; int n4;
    switch (blockIdx.y) {
        case 0:  s = x;  d = xb;  n4 = M_TOTAL * D_MODEL / 4; break;
        case 1:  s = wq; d = wqb; n4 = D_MODEL * D_MODEL / 4; break;
        case 2:  s = wk; d = wkb; n4 = D_MODEL * D_MODEL / 4; break;
        case 3:  s = wv; d = wvb; n4 = D_MODEL * D_MODEL / 4; break;
        default: s = wo; d = wob; n4 = D_MODEL * D_MODEL / 4; break;
    }
    const int stride = gridDim.x * blockDim.x;
    for (int i = blockIdx.x * blockDim.x + threadIdx.x; i < n4; i += stride) {
        float4 v = reinterpret_cast<const float4*>(s)[i];
        ushort4 u;
        u.x = f2bf(v.x); u.y = f2bf(v.y); u.z = f2bf(v.z); u.w = f2bf(v.w);
        reinterpret_cast<ushort4*>(d)[i] = u;
    }
}

// ---------------------------------------------------------------------------
// bf16 MFMA GEMM v2 (unchanged from round 6): BM=128 BN=64 BK=64, dbuf
// prefetch, pre-swizzled global_load_lds, XCD-chunked flat decode.
// ---------------------------------------------------------------------------
template<int EPI>
__global__ __launch_bounds__(256)
void gemm_mfma(const ushort* __restrict__ A,
               const ushort* __restrict__ W0, const float* __restrict__ b0, void* __restrict__ C0,
               const ushort* __restrict__ W1, const float* __restrict__ b1, void* __restrict__ C1,
               const ushort* __restrict__ W2, const float* __restrict__ b2, void* __restrict__ C2)
{
    constexpr int K = D_MODEL;

    __shared__ ushort As[2][128 * 64];   // 32 KB
    __shared__ ushort Bs[2][64 * 64];    // 16 KB

    const int id  = blockIdx.x;
    const int xcd = id & 7;
    const int j   = id >> 3;
    const int mt  = xcd * 4 + (j & 3);
    const int ntz = j >> 2;
    const int nt  = ntz & 15;
    const int z   = ntz >> 4;

    const ushort* W    = W0;
    const float*  bias = b0;
    void*         C    = C0;
    if (z == 1) { W = W1; bias = b1; C = C1; }
    else if (z == 2) { W = W2; bias = b2; C = C2; }

    const int m0 = mt * 128;
    const int n0 = nt * 64;

    const int tid  = threadIdx.x;
    const int w    = tid >> 6;
    const int lane = tid & 63;
    const int lr   = lane & 15;
    const int lc   = lane >> 4;
    const int wr   = w >> 1;
    const int wc   = w & 1;

    const int rsub = lane >> 3;
    const int csw  = ((lane & 7) ^ rsub) << 3;

    const ushort* gA = A + (size_t)(m0 + w * 8 + rsub) * K + csw;
    const ushort* gB = W + (size_t)(n0 + w * 8 + rsub) * K + csw;

    f32x4 acc[4][2];
#pragma unroll
    for (int m = 0; m < 4; ++m)
#pragma unroll
        for (int n = 0; n < 2; ++n) acc[m][n] = (f32x4)0.0f;

#pragma unroll
    for (int ca = 0; ca < 4; ++ca)
        gload16(gA + (size_t)(32 * ca) * K, &As[0][(w + 4 * ca) * 512]);
#pragma unroll
    for (int cb = 0; cb < 2; ++cb)
        gload16(gB + (size_t)(32 * cb) * K, &Bs[0][(w + 4 * cb) * 512]);
    __syncthreads();

    const int swz = (lr & 7) << 4;
    int buf = 0;
    for (int it = 0; it < 16; ++it) {
        if (it < 15) {
            const int kn = (it + 1) * 64;
#pragma unroll
            for (int ca = 0; ca < 4; ++ca)
                gload16(gA + (size_t)(32 * ca) * K + kn, &As[buf ^ 1][(w + 4 * ca) * 512]);
#pragma unroll
            for (int cb = 0; cb < 2; ++cb)
                gload16(gB + (size_t)(32 * cb) * K + kn, &Bs[buf ^ 1][(w + 4 * cb) * 512]);
        }

        short8 af[4][2], bfr[2][2];
#pragma unroll
        for (int m = 0; m < 4; ++m) {
            const int rbyte = (wr * 64 + m * 16 + lr) * 128;
#pragma unroll
            for (int kk = 0; kk < 2; ++kk)
                af[m][kk] = *reinterpret_cast<const short8*>(
                    &As[buf][(rbyte + ((kk * 64 + lc * 16) ^ swz)) >> 1]);
        }
#pragma unroll
        for (int n = 0; n < 2; ++n) {
            const int rbyte = (wc * 32 + n * 16 + lr) * 128;
#pragma unroll
            for (int kk = 0; kk < 2; ++kk)
                bfr[n][kk] = *reinterpret_cast<const short8*>(
                    &Bs[buf][(rbyte + ((kk * 64 + lc * 16) ^ swz)) >> 1]);
        }
#pragma unroll
        for (int kk = 0; kk < 2; ++kk)
#pragma unroll
            for (int m = 0; m < 4; ++m)
#pragma unroll
                for (int n = 0; n < 2; ++n)
                    acc[m][n] = __builtin_amdgcn_mfma_f32_16x16x32_bf16(
                        af[m][kk], bfr[n][kk], acc[m][n], 0, 0, 0);

        __syncthreads();
        buf ^= 1;
    }

    float bv[2];
#pragma unroll
    for (int n = 0; n < 2; ++n) bv[n] = bias[n0 + wc * 32 + n * 16 + lr];
    const int row_base = m0 + wr * 64;

    if (EPI == 0) {
        float* Cf = (float*)C;
#pragma unroll
        for (int m = 0; m < 4; ++m)
#pragma unroll
        for (int r = 0; r < 4; ++r) {
            const int row = row_base + m * 16 + lc * 4 + r;
#pragma unroll
            for (int n = 0; n < 2; ++n)
                Cf[(size_t)row * D_MODEL + n0 + wc * 32 + n * 16 + lr] =
                    acc[m][n][r] + bv[n];
        }
    } else {
        ushort* Cu = (ushort*)C;
        const bool vt   = (z == 2);
        const float osc = (z == 0) ? QSCALE : 1.0f;
#pragma unroll
        for (int m = 0; m < 4; ++m) {
            const int row4 = row_base + m * 16 + lc * 4;
            const int bb = row4 >> 11;
            const int ss = row4 & 2047;
            const size_t bhbase = (size_t)bb * N_HEADS;
#pragma unroll
            for (int n = 0; n < 2; ++n) {
                const int col = n0 + wc * 32 + n * 16 + lr;
                const int h = col >> 6, d = col & 63;
                if (vt) {
                    ushort4 u;
                    u.x = f2bf(acc[m][n][0] + bv[n]);
                    u.y = f2bf(acc[m][n][1] + bv[n]);
                    u.z = f2bf(acc[m][n][2] + bv[n]);
                    u.w = f2bf(acc[m][n][3] + bv[n]);
                    *reinterpret_cast<ushort4*>(
                        &Cu[((bhbase + h) * D_KK + d) * SEQ + ss]) = u;
                } else {
#pragma unroll
                    for (int r = 0; r < 4; ++r)
                        Cu[((bhbase + h) * SEQ + ss + r) * D_KK + d] =
                            f2bf((acc[m][n][r] + bv[n]) * osc);
                }
            }
        }
    }
}

// ---------------------------------------------------------------------------
// MFMA flash attention v4: v3 inner loop (swapped QK^T, exp2, defer-max,
// peeled diagonal, dbuf staging) + uniform work pairing: each block handles
// q-blocks {qx, 31-qx} = constant 33 tiles. 512 blocks, no tail imbalance.
// ---------------------------------------------------------------------------
__global__ __launch_bounds__(256, 4)
void attn_mfma_kernel(const ushort* __restrict__ Qb, const ushort* __restrict__ Kb,
                      const ushort* __restrict__ Vt, ushort* __restrict__ Ob)
{
    __shared__ ushort Ks[2][4096];
    __shared__ ushort Vs[2][4096];
    __shared__ ushort P_lds[4][1024];

    const int tid  = threadIdx.x;
    const int w    = tid >> 6;
    const int lane = tid & 63;
    const int lr   = lane & 15;
    const int lc   = lane >> 4;

    // 512 = 8 xcd * 4 bh * 16 q-pairs
    const int id  = blockIdx.x;
    const int xcd = id & 7;
    const int j   = id >> 3;             // 0..63
    const int bh  = xcd * 4 + (j & 3);
    const int qx  = j >> 2;              // 0..15
    const int b   = bh >> 4;
    const int h   = bh & 15;

    const ushort* Kbase = Kb + (size_t)bh * SEQ * D_KK;
    const ushort* Vbase = Vt + (size_t)bh * D_KK * SEQ;

    const int rsub = lane >> 3;
    const int csw  = ((lane & 7) ^ rsub) << 3;

    ushort* Pw     = &P_lds[w][0];
    const int sw_w = (lr & 7) << 4;

    for (int half = 0; half < 2; ++half) {
        const int qb  = half ? (31 - qx) : qx;
        const int q0  = qb * 64;
        const int qr0 = q0 + w * 16;
        const int nt  = qb + 1;

        const ushort* Qp = Qb + ((size_t)bh * SEQ + qr0 + lr) * D_KK + lc * 8;
        const short8 qa0 = *reinterpret_cast<const short8*>(Qp);
        const short8 qa1 = *reinterpret_cast<const short8*>(Qp + 32);

        f32x4 acc_o[4];
#pragma unroll
        for (int t = 0; t < 4; ++t) acc_o[t] = (f32x4)0.0f;
        float m_run = -1e30f;
        float l_run = 0.0f;

        // prologue: stage tile 0 -> buf 0
#pragma unroll
        for (int cc = 0; cc < 2; ++cc) {
            const int c = w + cc * 4;
            gload16(Kbase + (size_t)(c * 8 + rsub) * D_KK + csw, &Ks[0][c * 512]);
            gload16(Vbase + (size_t)(c * 8 + rsub) * SEQ + csw,  &Vs[0][c * 512]);
        }
        __syncthreads();

        auto tile_body = [&](int buf, auto maskc) {
            constexpr bool MASK = decltype(maskc)::value;
            const ushort* Ksb = &Ks[buf][0];
            const ushort* Vsb = &Vs[buf][0];

            f32x4 s[4];
#pragma unroll
            for (int t = 0; t < 4; ++t) {
                const int rbyte = (t * 16 + lr) * 128;
                const short8 kb0 = *reinterpret_cast<const short8*>(
                    &Ksb[(rbyte + ((lc * 16) ^ sw_w)) >> 1]);
                const short8 kb1 = *reinterpret_cast<const short8*>(
                    &Ksb[(rbyte + ((64 + lc * 16) ^ sw_w)) >> 1]);
                f32x4 a = (f32x4)0.0f;
                a = __builtin_amdgcn_mfma_f32_16x16x32_bf16(kb0, qa0, a, 0, 0, 0);
                a = __builtin_amdgcn_mfma_f32_16x16x32_bf16(kb1, qa1, a, 0, 0, 0);
                s[t] = a;
            }

            float tmax = -1e30f;
#pragma unroll
            for (int t = 0; t < 4; ++t)
#pragma unroll
                for (int r = 0; r < 4; ++r) {
                    if (MASK) {
                        const int kl = t * 16 + lc * 4 + r;
                        if (kl > w * 16 + lr) s[t][r] = -1e30f;
                    }
                    tmax = fmaxf(tmax, s[t][r]);
                }
            tmax = fmaxf(tmax, __shfl_xor(tmax, 16));
            tmax = fmaxf(tmax, __shfl_xor(tmax, 32));

            if (!__all(tmax <= m_run + 8.0f)) {
                const float mnew = fmaxf(m_run, tmax);
                const float corr = __builtin_amdgcn_exp2f(m_run - mnew);
                m_run = mnew;
                l_run *= corr;
                float cr[4];
#pragma unroll
                for (int r = 0; r < 4; ++r) cr[r] = __shfl(corr, lc * 4 + r, 16);
#pragma unroll
                for (int t = 0; t < 4; ++t)
#pragma unroll
                    for (int r = 0; r < 4; ++r) acc_o[t][r] *= cr[r];
            }

            float rsum = 0.0f;
#pragma unroll
            for (int t = 0; t < 4; ++t) {
#pragma unroll
                for (int r = 0; r < 4; ++r) {
                    const float p = __builtin_amdgcn_exp2f(s[t][r] - m_run);
                    s[t][r] = p;
                    rsum += p;
                }
                const unsigned lo = packbf(s[t][0], s[t][1]);
                const unsigned hi = packbf(s[t][2], s[t][3]);
                *reinterpret_cast<uint2*>(
                    &Pw[(lr * 128 + ((t * 32 + lc * 8) ^ sw_w)) >> 1]) =
                    make_uint2(lo, hi);
            }
            rsum += __shfl_xor(rsum, 16);
            rsum += __shfl_xor(rsum, 32);
            l_run += rsum;

            const short8 pa0 = *reinterpret_cast<const short8*>(
                &Pw[(lr * 128 + ((lc * 16) ^ sw_w)) >> 1]);
            const short8 pa1 = *reinterpret_cast<const short8*>(
                &Pw[(lr * 128 + ((64 + lc * 16) ^ sw_w)) >> 1]);

#pragma unroll
            for (int t = 0; t < 4; ++t) {
                const int rbyte = (t * 16 + lr) * 128;
                const short8 vb0 = *reinterpret_cast<const short8*>(
                    &Vsb[(rbyte + ((lc * 16) ^ sw_w)) >> 1]);
                const short8 vb1 = *reinterpret_cast<const short8*>(
                    &Vsb[(rbyte + ((64 + lc * 16) ^ sw_w)) >> 1]);
                acc_o[t] = __builtin_amdgcn_mfma_f32_16x16x32_bf16(
                        pa0, vb0, acc_o[t], 0, 0, 0);
                acc_o[t] = __builtin_amdgcn_mfma_f32_16x16x32_bf16(
                        pa1, vb1, acc_o[t], 0, 0, 0);
            }
        };

        int buf = 0;
        for (int it = 0; it < nt - 1; ++it) {
            const int kn = (it + 1) * 64;
#pragma unroll
            for (int cc = 0; cc < 2; ++cc) {
                const int c = w + cc * 4;
                gload16(Kbase + (size_t)(kn + c * 8 + rsub) * D_KK + csw,
                        &Ks[buf ^ 1][c * 512]);
                gload16(Vbase + (size_t)(c * 8 + rsub) * SEQ + kn + csw,
                        &Vs[buf ^ 1][c * 512]);
            }
            tile_body(buf, std::integral_constant<bool, false>{});
            __syncthreads();
            buf ^= 1;
        }
        tile_body(buf, std::integral_constant<bool, true>{});

        const float linv = 1.0f / l_run;
        float invr[4];
#pragma unroll
        for (int r = 0; r < 4; ++r) invr[r] = __shfl(linv, lc * 4 + r, 16);
#pragma unroll
        for (int r = 0; r < 4; ++r) {
            const int qrow = qr0 + lc * 4 + r;
            ushort* Op = Ob + ((size_t)b * SEQ + qrow) * D_MODEL + h * D_KK;
#pragma unroll
            for (int t = 0; t < 4; ++t)
                Op[t * 16 + lr] = f2bf(acc_o[t][r] * invr[r]);
        }

        if (half == 0) __syncthreads();   // all waves done with K/V bufs
    }
}

// ---------------------------------------------------------------------------
extern "C" void kernel_launch(void* const* d_in, const int* in_sizes, int n_in,
                              void* d_out, int out_size, void* d_ws, size_t ws_size,
                              hipStream_t stream)
{
    const float* x  = (const float*)d_in[0];
    const float* Wq = (const float*)d_in[2];
    const float* bq = (const float*)d_in[3];
    const float* Wk = (const float*)d_in[4];
    const float* bk = (const float*)d_in[5];
    const float* Wv = (const float*)d_in[6];
    const float* bv = (const float*)d_in[7];
    const float* Wo = (const float*)d_in[8];
    const float* bo = (const float*)d_in[9];
    float* out = (float*)d_out;

    const size_t TSZ = (size_t)M_TOTAL * D_MODEL;
    const size_t WSZ = (size_t)D_MODEL * D_MODEL;
    ushort* xb  = (ushort*)d_ws;
    ushort* Wqb = xb  + TSZ;
    ushort* Wkb = Wqb + WSZ;
    ushort* Wvb = Wkb + WSZ;
    ushort* Wob = Wvb + WSZ;
    ushort* Qb  = Wob + WSZ;
    ushort* Kb  = Qb  + TSZ;
    ushort* Vt  = Kb  + TSZ;
    ushort* Ob  = Vt  + TSZ;

    dim3 blk(256);
    cvt_kernel<<<dim3(256, 5), blk, 0, stream>>>(x, Wq, Wk, Wv, Wo,
                                                 xb, Wqb, Wkb, Wvb, Wob);

    // QKV: 32 mt x 16 nt x 3 z = 1536 blocks (flat, XCD-chunked decode)
    gemm_mfma<1><<<dim3(1536), blk, 0, stream>>>(xb, Wqb, bq, Qb,
                                                     Wkb, bk, Kb,
                                                     Wvb, bv, Vt);

    attn_mfma_kernel<<<dim3(512), blk, 0, stream>>>(Qb, Kb, Vt, Ob);

    // O-proj: 32 mt x 16 nt = 512 blocks
    gemm_mfma<0><<<dim3(512), blk, 0, stream>>>(Ob, Wob, bo, out,
                                                    Wob, bo, out,
                                                    Wob, bo, out);
}